// Round 10
// baseline (50.197 us; speedup 1.0000x reference)
//
#include <hip/hip_runtime.h>
#include <hip/hip_bf16.h>

typedef float f32x4 __attribute__((ext_vector_type(4)));

// Producer/consumer wave-specialized ternary conv1d.
// y[b,l,f] = bias[f] + sum_k wq[k,f] * x[b, l+k-7]   (SAME pad: lo=7, hi=8)
// Block = 512 threads (8 waves), owns 512 consecutive l. Waves 0-3 PRODUCE
// conv outputs into LDS chunks (32 l x 256 f = 32KB, double-buffered); waves
// 4-7 CONSUME: pure ds_read_b128 -> global_store_dwordx4 burst streams
// (memset-shaped, no compute between stores). One barrier per chunk,
// produce(c+1) || consume(c) on opposite buffers.
// Grid 512 = 32 b x 16 groups -> 2 blocks/CU (LDS 66KB), all resident.
// alpha: per-wave butterfly over producer's 64 weights/lane (bit-identical).
__global__ __launch_bounds__(512, 2) void ternary_conv1d_pc(
    const float* __restrict__ x,   // (B, L)
    const float* __restrict__ w,   // (16, 256) raw
    const float* __restrict__ bias,// (256)
    float* __restrict__ y,         // (B, L, 256)
    int L) {
    const int t    = threadIdx.x;
    const int lane = t & 63;
    const int wid  = t >> 6;          // 0..7
    const int bid  = blockIdx.x;
    const int b    = bid >> 4;        // 16 groups per batch
    const int g    = bid & 15;
    const int lbase = g * 512;

    __shared__ float xs[528];         // xs[j] = x[b, lbase-7+j], j=0..526
    __shared__ float buf[2][32][256]; // double-buffered 32-l output chunks

    // ---- stage x window (all threads) ----
    const size_t xb = (size_t)b * L;
    for (int j = t; j < 527; j += 512) {
        int gl = lbase - 7 + j;
        xs[j] = (gl >= 0 && gl < L) ? x[xb + gl] : 0.f;
    }

    // ---- producers: weights + alpha + ternarize (consumers skip) ----
    f32x4 wq[16];
    f32x4 bv;
    if (wid < 4) {
        float s = 0.f;
#pragma unroll
        for (int k = 0; k < 16; ++k) {
            f32x4 v = *reinterpret_cast<const f32x4*>(w + k * 256 + lane * 4);
            wq[k] = v;
            s += fabsf(v.x) + fabsf(v.y) + fabsf(v.z) + fabsf(v.w);
        }
#pragma unroll
        for (int m = 1; m < 64; m <<= 1) s += __shfl_xor(s, m, 64);
        const float alpha = s * (1.0f / 4096.0f);
        const float thr = 0.7f * alpha;
#pragma unroll
        for (int k = 0; k < 16; ++k) {
            f32x4 v = wq[k], q;
#pragma unroll
            for (int c = 0; c < 4; ++c) {
                float vc = v[c];
                q[c] = (fabsf(vc) < thr) ? 0.f
                     : (vc > 0.f ? alpha : (vc < 0.f ? -alpha : 0.f));
            }
            wq[k] = q;
        }
        bv = *reinterpret_cast<const f32x4*>(bias + lane * 4);
    }

    __syncthreads();                  // xs ready (before any global store)

    // produce chunk c: producer wave wid computes rows r0..r0+7 (8 l) into buf[c&1]
    auto produce = [&](int c) {
        const int cb = c & 1;
        const int r0 = wid * 8;
        const int base = c * 32 + r0; // xs window start: xs[base+i .. base+i+15]
        float xw[16];
#pragma unroll
        for (int j = 0; j < 16; ++j) xw[j] = xs[base + j];
#pragma unroll
        for (int i = 0; i < 8; ++i) {
            f32x4 acc = bv;
#pragma unroll
            for (int k = 0; k < 16; ++k) acc += wq[k] * xw[k];
            *reinterpret_cast<f32x4*>(&buf[cb][r0 + i][lane * 4]) = acc;
            if (i < 7) {
#pragma unroll
                for (int j = 0; j < 15; ++j) xw[j] = xw[j + 1];
                xw[15] = xs[base + i + 16];
            }
        }
    };

    // consume chunk c: consumer wave streams 8 rows, back-to-back 1KB stores
    auto consume = [&](int c) {
        const int cb = c & 1;
        const int r0 = (wid - 4) * 8;
        float* out0 = y + ((size_t)b * L + lbase + c * 32 + r0) * 256 + lane * 4;
#pragma unroll
        for (int i = 0; i < 8; ++i) {
            f32x4 v = *reinterpret_cast<const f32x4*>(&buf[cb][r0 + i][lane * 4]);
            *reinterpret_cast<f32x4*>(out0 + (size_t)i * 256) = v;
        }
    };

    if (wid < 4) produce(0);
    __syncthreads();                  // chunk 0 ready

    for (int c = 0; c < 16; ++c) {
        if (wid < 4) {
            if (c < 15) produce(c + 1);
        } else {
            consume(c);
        }
        __syncthreads();              // chunk c+1 ready & chunk c consumed
    }
}

extern "C" void kernel_launch(void* const* d_in, const int* in_sizes, int n_in,
                              void* d_out, int out_size, void* d_ws, size_t ws_size,
                              hipStream_t stream) {
    const float* x = (const float*)d_in[0];   // (32, 8192, 1)
    const float* w = (const float*)d_in[1];   // (16, 1, 256)
    const float* b = (const float*)d_in[2];   // (256,)
    float* y = (float*)d_out;                 // (32, 8192, 256)

    const int B = 32;
    const int L = in_sizes[0] / B;            // 8192

    ternary_conv1d_pc<<<B * 16, 512, 0, stream>>>(x, w, b, y, L);
}

// Round 11
// 48.978 us; speedup vs baseline: 1.0249x; 1.0249x over previous
//
#include <hip/hip_runtime.h>
#include <hip/hip_bf16.h>

typedef float f32x4 __attribute__((ext_vector_type(4)));

// Fully fused ternary-quant + conv1d, persistent blocks. (Ledger-best: R9.)
// y[b,l,f] = bias[f] + sum_k wq[k,f] * x[b, l+k-7]   (SAME pad: lo=7, hi=8)
// Grid 1024 = 32 b x 32 groups (4 blocks/CU, ALL resident, one prologue each):
// block owns 256 consecutive l = two 128-l tiles; both x windows staged in the
// prologue (xs0/xs1), single barrier BEFORE first store, then 512 stores
// stream uninterrupted. Wave ls owns contiguous 32-l per tile. Thread t:
// fg = t&63 owns f = 4*fg..4*fg+3 (plain f32x4 stores — nt was -16% (R3)).
// alpha: per-wave butterfly (bit-identical across waves), no LDS reduce.
// Ruled out by A/B: barrier drains (R6), occupancy cap (R7), per-wave store
// contiguity (R8), producer/consumer store specialization (R10: +1.3us).
__global__ __launch_bounds__(256, 4) void ternary_conv1d_fused(
    const float* __restrict__ x,   // (B, L)
    const float* __restrict__ w,   // (16, 256) raw
    const float* __restrict__ bias,// (256)
    float* __restrict__ y,         // (B, L, 256)
    int L) {
    const int t  = threadIdx.x;
    const int fg = t & 63;
    const int ls = t >> 6;            // wave id 0..3
    const int bid = blockIdx.x;
    const int b  = bid >> 5;          // 32 groups per batch
    const int g  = bid & 31;
    const int lbase = g * 256;

    __shared__ float xs0[144];        // x[b, lbase-7   + j], j=0..142 (tile0)
    __shared__ float xs1[144];        // x[b, lbase+121 + j], j=0..142 (tile1)

    // ---- stage both x windows (286 loads over 256 threads) ----
    const size_t xb = (size_t)b * L;
#pragma unroll
    for (int j = t; j < 286; j += 256) {
        int gl = (j < 143) ? (lbase - 7 + j) : (lbase + 121 + (j - 143));
        float v = (gl >= 0 && gl < L) ? x[xb + gl] : 0.f;
        if (j < 143) xs0[j] = v; else xs1[j - 143] = v;
    }

    // ---- load weights + per-lane |w| partial ----
    f32x4 wv[16];
    float s = 0.f;
#pragma unroll
    for (int k = 0; k < 16; ++k) {
        f32x4 v = *reinterpret_cast<const f32x4*>(w + k * 256 + fg * 4);
        wv[k] = v;
        s += fabsf(v.x) + fabsf(v.y) + fabsf(v.z) + fabsf(v.w);
    }
    // wave butterfly: identical full sum in every lane of every wave
#pragma unroll
    for (int m = 1; m < 64; m <<= 1) s += __shfl_xor(s, m, 64);
    const float alpha = s * (1.0f / 4096.0f);
    const float thr = 0.7f * alpha;

    // ---- ternarize in registers ----
#pragma unroll
    for (int k = 0; k < 16; ++k) {
        f32x4 v = wv[k], q;
#pragma unroll
        for (int c = 0; c < 4; ++c) {
            float vc = v[c];
            q[c] = (fabsf(vc) < thr) ? 0.f
                 : (vc > 0.f ? alpha : (vc < 0.f ? -alpha : 0.f));
        }
        wv[k] = q;
    }
    const f32x4 bv = *reinterpret_cast<const f32x4*>(bias + fg * 4);

    __syncthreads();                  // single barrier, before any store

    float xw[16];
    f32x4* outp;

    // ---- tile 0: wave ls stores l in [lbase+32ls, +32), contiguous 1KB/iter ----
#pragma unroll
    for (int j = 0; j < 16; ++j) xw[j] = xs0[ls * 32 + j];
    outp = reinterpret_cast<f32x4*>(y) + ((size_t)b * L + lbase + ls * 32) * 64 + fg;
#pragma unroll 4
    for (int i = 0; i < 32; ++i) {
        f32x4 acc = bv;
#pragma unroll
        for (int k = 0; k < 16; ++k) acc += wv[k] * xw[k];
        *outp = acc;
        outp += 64;
        if (i < 31) {
#pragma unroll
            for (int j = 0; j < 15; ++j) xw[j] = xw[j + 1];
            xw[15] = xs0[ls * 32 + i + 16];
        }
    }

    // ---- tile 1: l in [lbase+128+32ls, +32); xs1 idx = l - (lbase+121) ----
#pragma unroll
    for (int j = 0; j < 16; ++j) xw[j] = xs1[ls * 32 + j];
    outp = reinterpret_cast<f32x4*>(y) + ((size_t)b * L + lbase + 128 + ls * 32) * 64 + fg;
#pragma unroll 4
    for (int i = 0; i < 32; ++i) {
        f32x4 acc = bv;
#pragma unroll
        for (int k = 0; k < 16; ++k) acc += wv[k] * xw[k];
        *outp = acc;
        outp += 64;
        if (i < 31) {
#pragma unroll
            for (int j = 0; j < 15; ++j) xw[j] = xw[j + 1];
            xw[15] = xs1[ls * 32 + i + 16];
        }
    }
}

extern "C" void kernel_launch(void* const* d_in, const int* in_sizes, int n_in,
                              void* d_out, int out_size, void* d_ws, size_t ws_size,
                              hipStream_t stream) {
    const float* x = (const float*)d_in[0];   // (32, 8192, 1)
    const float* w = (const float*)d_in[1];   // (16, 1, 256)
    const float* b = (const float*)d_in[2];   // (256,)
    float* y = (float*)d_out;                 // (32, 8192, 256)

    const int B = 32;
    const int L = in_sizes[0] / B;            // 8192

    ternary_conv1d_fused<<<B * 32, 256, 0, stream>>>(x, w, b, y, L);
}